// Round 3
// baseline (1688.936 us; speedup 1.0000x reference)
//
#include <hip/hip_runtime.h>
#include <hip/hip_bf16.h>
#include <stdint.h>

// Problem constants (from reference)
#define NN    50000   // nodes
#define EE    800000  // edges
#define IN_C  128     // in_channels
#define ED_C  64      // edge_dim
#define HID_C 256     // hidden
#define BB    128     // graphs
#define KK    1000    // classes
#define G1_C  128     // gate hidden

// Dtype model (R1/R2 forensics):
//  - float inputs are fp32 (R1: bf16-pair reads of fp32 data -> NaN)
//  - index inputs are int32
//  - OUTPUT is fp32 (R2: bf16 writes left pooled region = memset zeros ->
//    error exactly 454.0 == stub round; logits pair-read garbage 5.95)

__device__ __forceinline__ void atomicMaxFloat(float* addr, float val){
  int old = __float_as_int(*addr);
  while (__int_as_float(old) < val){
    int assumed = old;
    old = atomicCAS((int*)addr, assumed, __float_as_int(val));
    if (old == assumed) break;
  }
}

// ---------------- init: zero agg/denom/pooled, gmax=-1e30 ----------------
__global__ __launch_bounds__(256) void k_init(float* __restrict__ agg,
                                              float* __restrict__ gmax,
                                              float* __restrict__ denom,
                                              float* __restrict__ pooled){
  size_t i = (size_t)blockIdx.x * 256 + threadIdx.x;
  if (i < (size_t)NN * IN_C) agg[i] = 0.f;
  if (i < BB){ gmax[i] = -1e30f; denom[i] = 0.f; }
  if (i < BB * HID_C) pooled[i] = 0.f;
}

// ---------------- edge stage: m = relu(x[src] + ea@We + be); agg[dst] += m
__global__ __launch_bounds__(128) void k_edge(
    const float* __restrict__ x, const int* __restrict__ ei,
    const float* __restrict__ edge_attr,
    const float* __restrict__ We, const float* __restrict__ be,
    float* __restrict__ agg)
{
  const int t = threadIdx.x;
  float w[ED_C];
#pragma unroll
  for (int k = 0; k < ED_C; ++k) w[k] = We[k * IN_C + t];
  const float bev = be[t];
  int e0 = blockIdx.x * 128;          // grid = 6250 covers EE exactly
  int e1 = e0 + 128; if (e1 > EE) e1 = EE;
  for (int e = e0; e < e1; ++e){
    int src = ei[e];
    int dst = ei[EE + e];
    const float* ea = edge_attr + (size_t)e * ED_C;
    float acc = bev;
#pragma unroll
    for (int k = 0; k < ED_C; ++k) acc = fmaf(ea[k], w[k], acc);
    float m = acc + x[(size_t)src * IN_C + t];
    m = m > 0.f ? m : 0.f;
    atomicAdd(&agg[(size_t)dst * IN_C + t], m);
  }
}

// ---------------- h0 = agg + x (in place into agg, f32) ----------------
__global__ __launch_bounds__(256) void k_h0(float* __restrict__ agg,
                                            const float* __restrict__ x){
  size_t i = (size_t)blockIdx.x * 256 + threadIdx.x;
  if (i < (size_t)NN * IN_C) agg[i] += x[i];
}

// ---------------- generic row-GEMM: out[r][t] (=|+=) sum_k A[r][aoff+k]*W[k][t]
template<int KSEG, int NCOL, bool INIT, bool RELU>
__global__ __launch_bounds__(NCOL) void k_rowgemm(
    const float* __restrict__ A, int lda, int aoff,
    const float* __restrict__ W,
    const float* __restrict__ bias,
    float* __restrict__ out, int nrows)
{
  const int t = threadIdx.x;
  float w[KSEG];
#pragma unroll
  for (int k = 0; k < KSEG; ++k) w[k] = W[k * NCOL + t];
  float bv = 0.f;
  if (INIT) bv = bias[t];
  for (int r = blockIdx.x; r < nrows; r += gridDim.x){
    const float* ar = A + (size_t)r * lda + aoff;
    float acc = 0.f;
#pragma unroll
    for (int k = 0; k < KSEG; ++k) acc = fmaf(ar[k], w[k], acc);
    float* po = out + (size_t)r * NCOL + t;
    float v = INIT ? (acc + bv) : (*po + acc);
    if (RELU) v = v > 0.f ? v : 0.f;
    *po = v;
  }
}

// ---------------- gate2: gate[r] = g1[r,:128] . Wg2 + bg2 (1 wave/row) ----
__global__ __launch_bounds__(64) void k_gate2(const float* __restrict__ g1,
                                              const float* __restrict__ Wg2,
                                              const float* __restrict__ bg2,
                                              float* __restrict__ gate, int nrows){
  const int t = threadIdx.x;
  const float w0 = Wg2[t], w1 = Wg2[t + 64];
  const float bg = bg2[0];
  for (int r = blockIdx.x; r < nrows; r += gridDim.x){
    const float* ar = g1 + (size_t)r * G1_C;
    float p = ar[t] * w0 + ar[t + 64] * w1;
#pragma unroll
    for (int off = 32; off > 0; off >>= 1) p += __shfl_down(p, off);
    if (t == 0) gate[r] = p + bg;
  }
}

// ---------------- segment max (batch sorted; block pre-reduce) ----------
__global__ __launch_bounds__(256) void k_gmax(const float* __restrict__ gate,
                                              const int* __restrict__ batch,
                                              float* __restrict__ gmax, int nrows){
  __shared__ float red[256];
  const int tid = threadIdx.x;
  const int n0 = blockIdx.x * 256;
  const int n = n0 + tid;
  const int nlast = (n0 + 255 < nrows) ? n0 + 255 : nrows - 1;
  const int bmin = batch[n0], bmax = batch[nlast];
  float val = -3e38f; int b = bmax;
  if (n < nrows){ b = batch[n]; val = gate[n]; }
  for (int bb = bmin; bb <= bmax; ++bb){
    red[tid] = (b == bb) ? val : -3e38f;
    __syncthreads();
    for (int s = 128; s > 0; s >>= 1){
      if (tid < s) red[tid] = fmaxf(red[tid], red[tid + s]);
      __syncthreads();
    }
    if (tid == 0 && red[0] > -1e37f) atomicMaxFloat(&gmax[bb], red[0]);
    __syncthreads();
  }
}

// ---------------- a = exp(gate - gmax[b]); denom[b] += a ----------------
__global__ __launch_bounds__(256) void k_expsum(const float* __restrict__ gate,
                                                const int* __restrict__ batch,
                                                const float* __restrict__ gmax,
                                                float* __restrict__ aexp,
                                                float* __restrict__ denom, int nrows){
  __shared__ float red[256];
  const int tid = threadIdx.x;
  const int n0 = blockIdx.x * 256;
  const int n = n0 + tid;
  const int nlast = (n0 + 255 < nrows) ? n0 + 255 : nrows - 1;
  const int bmin = batch[n0], bmax = batch[nlast];
  float val = 0.f; int b = bmax;
  if (n < nrows){
    b = batch[n];
    val = expf(gate[n] - gmax[b]);
    aexp[n] = val;
  }
  for (int bb = bmin; bb <= bmax; ++bb){
    red[tid] = (b == bb) ? val : 0.f;
    __syncthreads();
    for (int s = 128; s > 0; s >>= 1){
      if (tid < s) red[tid] += red[tid + s];
      __syncthreads();
    }
    if (tid == 0 && red[0] != 0.f) atomicAdd(&denom[bb], red[0]);
    __syncthreads();
  }
}

// ---------------- pooled[b] += (a/denom[b]) * h2[n] ----------------
__global__ __launch_bounds__(256) void k_pool(const float* __restrict__ h2,
                                              const float* __restrict__ aexp,
                                              const float* __restrict__ denom,
                                              const int* __restrict__ batch,
                                              float* __restrict__ pooled, int nrows){
  const int c = threadIdx.x;
  const int n0 = blockIdx.x * 256;
  int n1 = n0 + 256; if (n1 > nrows) n1 = nrows;
  float acc = 0.f;
  int curb = batch[n0];
  for (int n = n0; n < n1; ++n){
    int b = batch[n];
    if (b != curb){
      atomicAdd(&pooled[(size_t)curb * HID_C + c], acc);
      acc = 0.f; curb = b;
    }
    float wgt = aexp[n] / denom[b];
    acc = fmaf(wgt, h2[(size_t)n * HID_C + c], acc);
  }
  atomicAdd(&pooled[(size_t)curb * HID_C + c], acc);
}

// ---------------- head: logits = pooled @ Wh + bh; emit both outputs (fp32)
__global__ __launch_bounds__(256) void k_head(const float* __restrict__ pooled,
                                              const float* __restrict__ Wh,
                                              const float* __restrict__ bh,
                                              float* __restrict__ out_logits,
                                              float* __restrict__ out_pooled){
  __shared__ float p[HID_C];
  const int b = blockIdx.x, t = threadIdx.x;
  float pv = pooled[(size_t)b * HID_C + t];
  p[t] = pv;
  out_pooled[(size_t)b * HID_C + t] = pv;
  __syncthreads();
  for (int c = t; c < KK; c += 256){
    float acc = bh[c];
#pragma unroll 8
    for (int k = 0; k < HID_C; ++k)
      acc = fmaf(p[k], Wh[k * KK + c], acc);
    out_logits[(size_t)b * KK + c] = acc;
  }
}

extern "C" void kernel_launch(void* const* d_in, const int* in_sizes, int n_in,
                              void* d_out, int out_size, void* d_ws, size_t ws_size,
                              hipStream_t stream) {
  const float* x   = (const float*)d_in[0];   // [N,128]
  const int*   ei  = (const int*)d_in[1];     // [2,E]: row0 src, row1 dst
  const float* ea  = (const float*)d_in[2];   // [E,64]
  const int*   batch = (const int*)d_in[3];   // [N] sorted
  const float* We  = (const float*)d_in[4];   // [64,128]
  const float* be  = (const float*)d_in[5];
  const float* W1  = (const float*)d_in[6];   // [128,256]
  const float* b1  = (const float*)d_in[7];
  const float* W2  = (const float*)d_in[8];   // [256,256]
  const float* b2  = (const float*)d_in[9];
  const float* Wg1 = (const float*)d_in[10];  // [256,128]
  const float* bg1 = (const float*)d_in[11];
  const float* Wg2 = (const float*)d_in[12];  // [128]
  const float* bg2 = (const float*)d_in[13];  // [1]
  const float* Wh  = (const float*)d_in[14];  // [256,1000]
  const float* bh  = (const float*)d_in[15];

  float* out_logits = (float*)d_out;
  float* out_pooled = out_logits + (size_t)BB * KK;

  // workspace layout (f32): agg(=h0) | h1(aliased by g1) | h2 | gate | aexp | gmax | denom | pooled
  float* agg    = (float*)d_ws;                    // N*128
  float* h1     = agg    + (size_t)NN * IN_C;      // N*256
  float* h2     = h1     + (size_t)NN * HID_C;     // N*256
  float* gate   = h2     + (size_t)NN * HID_C;     // N
  float* aexp   = gate   + NN;                     // N
  float* gmax   = aexp   + NN;                     // B
  float* denom  = gmax   + BB;                     // B
  float* pooled = denom  + BB;                     // B*256
  float* g1     = h1;                              // alias: h1 dead once h2 ready

  // 1. init accumulators (ws is re-poisoned 0xAA before every call)
  k_init<<<(NN * IN_C + 255) / 256, 256, 0, stream>>>(agg, gmax, denom, pooled);
  // 2. edge projection + message + scatter-add
  k_edge<<<EE / 128, 128, 0, stream>>>(x, ei, ea, We, be, agg);
  // 3. h0 = x + agg (in place)
  k_h0<<<(NN * IN_C + 255) / 256, 256, 0, stream>>>(agg, x);
  // 4. h1 = relu(h0 @ W1 + b1)
  k_rowgemm<IN_C, HID_C, true, true><<<2048, HID_C, 0, stream>>>(agg, IN_C, 0, W1, b1, h1, NN);
  // 5/6. h2 = h1 @ W2 + b2 (two K=128 passes)
  k_rowgemm<128, HID_C, true,  false><<<2048, HID_C, 0, stream>>>(h1, HID_C, 0,   W2,               b2, h2, NN);
  k_rowgemm<128, HID_C, false, false><<<2048, HID_C, 0, stream>>>(h1, HID_C, 128, W2 + 128 * HID_C, (const float*)0, h2, NN);
  // 7/8. g1 = relu(h2 @ Wg1 + bg1) (two K=128 passes; relu after 2nd)
  k_rowgemm<128, G1_C, true,  false><<<2048, G1_C, 0, stream>>>(h2, HID_C, 0,   Wg1,               bg1, g1, NN);
  k_rowgemm<128, G1_C, false, true ><<<2048, G1_C, 0, stream>>>(h2, HID_C, 128, Wg1 + 128 * G1_C,  (const float*)0, g1, NN);
  // 9. gate = g1 @ Wg2 + bg2
  k_gate2<<<2048, 64, 0, stream>>>(g1, Wg2, bg2, gate, NN);
  // 10-12. segment softmax + attention pooling
  k_gmax  <<<(NN + 255) / 256, 256, 0, stream>>>(gate, batch, gmax, NN);
  k_expsum<<<(NN + 255) / 256, 256, 0, stream>>>(gate, batch, gmax, aexp, denom, NN);
  k_pool  <<<(NN + 255) / 256, 256, 0, stream>>>(h2, aexp, denom, batch, pooled, NN);
  // 13. head + output emit
  k_head<<<BB, 256, 0, stream>>>(pooled, Wh, bh, out_logits, out_pooled);
}

// Round 4
// 932.206 us; speedup vs baseline: 1.8118x; 1.8118x over previous
//
#include <hip/hip_runtime.h>
#include <stdint.h>

// Problem constants
#define NN    50000
#define EE    800000
#define IN_C  128
#define ED_C  64
#define HID_C 256
#define BB    128
#define KK    1000
#define G1_C  128

// Dtype model (R1/R2 forensics): fp32 inputs, int32 indices, fp32 outputs.
// Threshold is 8 bf16-ulps (floor_eps_k=8) -> bf16 MFMA GEMMs are in-budget.

typedef __attribute__((ext_vector_type(8))) short bfrag;   // 8 x bf16 (4 VGPR)
typedef __attribute__((ext_vector_type(4))) float f4acc;   // 4 x f32 acc

__device__ __forceinline__ unsigned short f2bs(float f){   // f32 -> bf16 (RNE)
  unsigned u = __float_as_uint(f);
  return (unsigned short)((u + 0x7fffu + ((u >> 16) & 1u)) >> 16);
}
__device__ __forceinline__ float bs2f(unsigned short s){   // bf16 -> f32 exact
  return __uint_as_float(((unsigned)s) << 16);
}

__device__ __forceinline__ void atomicMaxFloat(float* addr, float val){
  int old = __float_as_int(*addr);
  while (__int_as_float(old) < val){
    int assumed = old;
    old = atomicCAS((int*)addr, assumed, __float_as_int(val));
    if (old == assumed) break;
  }
}

// ---------------- prep: cast+transpose weights to bf16 (Wt[n][k] = W[k][n]) --
__global__ __launch_bounds__(256) void k_prep(
    const float* __restrict__ We, const float* __restrict__ W1,
    const float* __restrict__ W2, const float* __restrict__ Wg1,
    unsigned short* __restrict__ Wet, unsigned short* __restrict__ W1t,
    unsigned short* __restrict__ W2t, unsigned short* __restrict__ Wg1t)
{
  int i = blockIdx.x * 256 + threadIdx.x;          // 0..65535
  if (i < 128 * 64){ int c = i >> 6, k = i & 63;  Wet[i]  = f2bs(We[k * 128 + c]); }
  if (i < 256 * 128){ int n = i >> 7, k = i & 127; W1t[i]  = f2bs(W1[k * 256 + n]); }
  if (i < 256 * 256){ int n = i >> 8, k = i & 255; W2t[i]  = f2bs(W2[k * 256 + n]); }
  if (i < 128 * 256){ int n = i >> 8, k = i & 255; Wg1t[i] = f2bs(Wg1[k * 128 + n]); }
}

// ---------------- init: zero agg/denom/pooled, gmax=-1e30 ----------------
__global__ __launch_bounds__(256) void k_init(float* __restrict__ agg,
                                              float* __restrict__ gmax,
                                              float* __restrict__ denom,
                                              float* __restrict__ pooled){
  size_t i = (size_t)blockIdx.x * 256 + threadIdx.x;
  if (i < (size_t)NN * IN_C) agg[i] = 0.f;
  if (i < BB){ gmax[i] = -1e30f; denom[i] = 0.f; }
  if (i < BB * HID_C) pooled[i] = 0.f;
}

// ---------------- edge stage (MFMA): proj = ea@We; m=relu(x[src]+proj+be);
// agg[dst] += m.  Block = 256 thr / 4 waves, tile = 128 edges x 128 channels.
// ea tile staged fp32->bf16 in LDS (72-ushort rows: 144B stride, 16B-aligned,
// 2-way-free bank pattern); Wet b-frags straight from global (L2-hot).
__global__ __launch_bounds__(256) void k_edge(
    const float* __restrict__ x, const int* __restrict__ ei,
    const float* __restrict__ edge_attr,
    const unsigned short* __restrict__ Wet, const float* __restrict__ be,
    float* __restrict__ agg)
{
  __shared__ unsigned short eaS[128 * 72];
  const int tid = threadIdx.x;
  const int e0 = blockIdx.x * 128;
#pragma unroll
  for (int t = 0; t < 8; ++t){                      // 2048 float4 total
    int f4 = t * 256 + tid;
    int er = f4 >> 4;                               // edge row 0..127
    int kk = (f4 & 15) * 4;                         // k offset 0..60
    const float4 v = *(const float4*)(edge_attr + (size_t)(e0 + er) * ED_C + kk);
    unsigned p0 = (unsigned)f2bs(v.x) | ((unsigned)f2bs(v.y) << 16);
    unsigned p1 = (unsigned)f2bs(v.z) | ((unsigned)f2bs(v.w) << 16);
    *(uint2*)&eaS[er * 72 + kk] = make_uint2(p0, p1);
  }
  __syncthreads();

  const int lane = tid & 63, wv = tid >> 6;
  const int q = lane >> 4, l15 = lane & 15;

  f4acc acc[2][8];
  const f4acc zz = {0.f, 0.f, 0.f, 0.f};
#pragma unroll
  for (int mt = 0; mt < 2; ++mt)
#pragma unroll
    for (int nt = 0; nt < 8; ++nt) acc[mt][nt] = zz;

#pragma unroll
  for (int ks = 0; ks < 2; ++ks){
    bfrag a[2], b[8];
#pragma unroll
    for (int mt = 0; mt < 2; ++mt){
      int m = wv * 32 + mt * 16 + l15;              // A: row = lane&15
      a[mt] = *(const bfrag*)&eaS[m * 72 + ks * 32 + q * 8];
    }
#pragma unroll
    for (int nt = 0; nt < 8; ++nt){
      int c = nt * 16 + l15;                        // B: col = lane&15 (B^T rows)
      b[nt] = *(const bfrag*)(Wet + c * ED_C + ks * 32 + q * 8);
    }
#pragma unroll
    for (int mt = 0; mt < 2; ++mt)
#pragma unroll
      for (int nt = 0; nt < 8; ++nt)
        acc[mt][nt] = __builtin_amdgcn_mfma_f32_16x16x32_bf16(a[mt], b[nt], acc[mt][nt], 0, 0, 0);
  }

  float bev[8];
#pragma unroll
  for (int nt = 0; nt < 8; ++nt) bev[nt] = be[nt * 16 + l15];

#pragma unroll
  for (int mt = 0; mt < 2; ++mt){
#pragma unroll
    for (int r = 0; r < 4; ++r){
      int m = wv * 32 + mt * 16 + q * 4 + r;        // D: row = 4*quad + reg
      int eg = e0 + m;
      int s = ei[eg], d = ei[EE + eg];
      const float* xr = x + (size_t)s * IN_C;
      float* ar = agg + (size_t)d * IN_C;
#pragma unroll
      for (int nt = 0; nt < 8; ++nt){
        int c = nt * 16 + l15;                      // D: col = lane&15
        float v = acc[mt][nt][r] + bev[nt] + xr[c];
        v = v > 0.f ? v : 0.f;
        atomicAdd(ar + c, v);
      }
    }
  }
}

// ---------------- h0 = agg + x -> bf16 ----------------
__global__ __launch_bounds__(256) void k_h0(const float* __restrict__ agg,
                                            const float* __restrict__ x,
                                            unsigned short* __restrict__ h0b){
  int i = blockIdx.x * 256 + threadIdx.x;
  if (i < NN * IN_C) h0b[i] = f2bs(agg[i] + x[i]);
}

// ---------------- MFMA GEMM, global-direct fragments (no LDS) ------------
// out[m][c] = A[m][:K] . Wt[c][:K] + bias[c]; block tile 64m x 128n, 4 waves
// in 2x2; per wave 32m x 64n = 2x4 16x16 tiles.
template<int K, bool RELU, bool OF32, bool OB16>
__global__ __launch_bounds__(256) void k_gemm(
    const unsigned short* __restrict__ A, const unsigned short* __restrict__ Wt,
    const float* __restrict__ bias, float* __restrict__ outf,
    unsigned short* __restrict__ outb, int M, int Ntot)
{
  const int tid = threadIdx.x;
  const int lane = tid & 63, wv = tid >> 6;
  const int wi = wv >> 1, wj = wv & 1;
  const int q = lane >> 4, l15 = lane & 15;
  const int mb = blockIdx.x * 64 + wi * 32;
  const int nb = blockIdx.y * 128 + wj * 64;

  f4acc acc[2][4];
  const f4acc zz = {0.f, 0.f, 0.f, 0.f};
#pragma unroll
  for (int mt = 0; mt < 2; ++mt)
#pragma unroll
    for (int nt = 0; nt < 4; ++nt) acc[mt][nt] = zz;

#pragma unroll
  for (int ks = 0; ks < K / 32; ++ks){
    bfrag a[2], b[4];
#pragma unroll
    for (int mt = 0; mt < 2; ++mt){
      int m = mb + mt * 16 + l15; if (m >= M) m = M - 1;
      a[mt] = *(const bfrag*)(A + (size_t)m * K + ks * 32 + q * 8);
    }
#pragma unroll
    for (int nt = 0; nt < 4; ++nt){
      int n = nb + nt * 16 + l15;
      b[nt] = *(const bfrag*)(Wt + (size_t)n * K + ks * 32 + q * 8);
    }
#pragma unroll
    for (int mt = 0; mt < 2; ++mt)
#pragma unroll
      for (int nt = 0; nt < 4; ++nt)
        acc[mt][nt] = __builtin_amdgcn_mfma_f32_16x16x32_bf16(a[mt], b[nt], acc[mt][nt], 0, 0, 0);
  }

#pragma unroll
  for (int nt = 0; nt < 4; ++nt){
    int c = nb + nt * 16 + l15;
    float bv = bias[c];
#pragma unroll
    for (int mt = 0; mt < 2; ++mt){
#pragma unroll
      for (int r = 0; r < 4; ++r){
        int m = mb + mt * 16 + q * 4 + r;
        if (m < M){
          float v = acc[mt][nt][r] + bv;
          if (RELU) v = v > 0.f ? v : 0.f;
          if (OF32) outf[(size_t)m * Ntot + c] = v;
          if (OB16) outb[(size_t)m * Ntot + c] = f2bs(v);
        }
      }
    }
  }
}

// ---------------- gate2: gate[r] = g1[r,:128] . Wg2 + bg2 (1 wave/row) ----
__global__ __launch_bounds__(64) void k_gate2(const float* __restrict__ g1,
                                              const float* __restrict__ Wg2,
                                              const float* __restrict__ bg2,
                                              float* __restrict__ gate, int nrows){
  const int t = threadIdx.x;
  const float w0 = Wg2[t], w1 = Wg2[t + 64];
  const float bg = bg2[0];
  for (int r = blockIdx.x; r < nrows; r += gridDim.x){
    const float* ar = g1 + (size_t)r * G1_C;
    float p = ar[t] * w0 + ar[t + 64] * w1;
#pragma unroll
    for (int off = 32; off > 0; off >>= 1) p += __shfl_down(p, off);
    if (t == 0) gate[r] = p + bg;
  }
}

// ---------------- segment max (batch sorted; block pre-reduce) ----------
__global__ __launch_bounds__(256) void k_gmax(const float* __restrict__ gate,
                                              const int* __restrict__ batch,
                                              float* __restrict__ gmax, int nrows){
  __shared__ float red[256];
  const int tid = threadIdx.x;
  const int n0 = blockIdx.x * 256;
  const int n = n0 + tid;
  const int nlast = (n0 + 255 < nrows) ? n0 + 255 : nrows - 1;
  const int bmin = batch[n0], bmax = batch[nlast];
  float val = -3e38f; int b = bmax;
  if (n < nrows){ b = batch[n]; val = gate[n]; }
  for (int bb = bmin; bb <= bmax; ++bb){
    red[tid] = (b == bb) ? val : -3e38f;
    __syncthreads();
    for (int s = 128; s > 0; s >>= 1){
      if (tid < s) red[tid] = fmaxf(red[tid], red[tid + s]);
      __syncthreads();
    }
    if (tid == 0 && red[0] > -1e37f) atomicMaxFloat(&gmax[bb], red[0]);
    __syncthreads();
  }
}

// ---------------- a = exp(gate - gmax[b]); denom[b] += a ----------------
__global__ __launch_bounds__(256) void k_expsum(const float* __restrict__ gate,
                                                const int* __restrict__ batch,
                                                const float* __restrict__ gmax,
                                                float* __restrict__ aexp,
                                                float* __restrict__ denom, int nrows){
  __shared__ float red[256];
  const int tid = threadIdx.x;
  const int n0 = blockIdx.x * 256;
  const int n = n0 + tid;
  const int nlast = (n0 + 255 < nrows) ? n0 + 255 : nrows - 1;
  const int bmin = batch[n0], bmax = batch[nlast];
  float val = 0.f; int b = bmax;
  if (n < nrows){
    b = batch[n];
    val = expf(gate[n] - gmax[b]);
    aexp[n] = val;
  }
  for (int bb = bmin; bb <= bmax; ++bb){
    red[tid] = (b == bb) ? val : 0.f;
    __syncthreads();
    for (int s = 128; s > 0; s >>= 1){
      if (tid < s) red[tid] += red[tid + s];
      __syncthreads();
    }
    if (tid == 0 && red[0] != 0.f) atomicAdd(&denom[bb], red[0]);
    __syncthreads();
  }
}

// ---------------- pooled[b] += (a/denom[b]) * h2[n]  (h2 in bf16) --------
__global__ __launch_bounds__(256) void k_pool(const unsigned short* __restrict__ h2b,
                                              const float* __restrict__ aexp,
                                              const float* __restrict__ denom,
                                              const int* __restrict__ batch,
                                              float* __restrict__ pooled, int nrows){
  const int c = threadIdx.x;
  const int n0 = blockIdx.x * 256;
  int n1 = n0 + 256; if (n1 > nrows) n1 = nrows;
  float acc = 0.f;
  int curb = batch[n0];
  for (int n = n0; n < n1; ++n){
    int b = batch[n];
    if (b != curb){
      atomicAdd(&pooled[(size_t)curb * HID_C + c], acc);
      acc = 0.f; curb = b;
    }
    float wgt = aexp[n] / denom[b];
    acc = fmaf(wgt, bs2f(h2b[(size_t)n * HID_C + c]), acc);
  }
  atomicAdd(&pooled[(size_t)curb * HID_C + c], acc);
}

// ---------------- head: logits = pooled @ Wh + bh; emit outputs (fp32) ---
__global__ __launch_bounds__(256) void k_head(const float* __restrict__ pooled,
                                              const float* __restrict__ Wh,
                                              const float* __restrict__ bh,
                                              float* __restrict__ out_logits,
                                              float* __restrict__ out_pooled){
  __shared__ float p[HID_C];
  const int b = blockIdx.x, t = threadIdx.x;
  float pv = pooled[(size_t)b * HID_C + t];
  p[t] = pv;
  out_pooled[(size_t)b * HID_C + t] = pv;
  __syncthreads();
  for (int c = t; c < KK; c += 256){
    float acc = bh[c];
#pragma unroll 8
    for (int k = 0; k < HID_C; ++k)
      acc = fmaf(p[k], Wh[k * KK + c], acc);
    out_logits[(size_t)b * KK + c] = acc;
  }
}

extern "C" void kernel_launch(void* const* d_in, const int* in_sizes, int n_in,
                              void* d_out, int out_size, void* d_ws, size_t ws_size,
                              hipStream_t stream) {
  const float* x   = (const float*)d_in[0];
  const int*   ei  = (const int*)d_in[1];
  const float* ea  = (const float*)d_in[2];
  const int*   batch = (const int*)d_in[3];
  const float* We  = (const float*)d_in[4];
  const float* be  = (const float*)d_in[5];
  const float* W1  = (const float*)d_in[6];
  const float* b1  = (const float*)d_in[7];
  const float* W2  = (const float*)d_in[8];
  const float* b2  = (const float*)d_in[9];
  const float* Wg1 = (const float*)d_in[10];
  const float* bg1 = (const float*)d_in[11];
  const float* Wg2 = (const float*)d_in[12];
  const float* bg2 = (const float*)d_in[13];
  const float* Wh  = (const float*)d_in[14];
  const float* bh  = (const float*)d_in[15];

  float* out_logits = (float*)d_out;
  float* out_pooled = out_logits + (size_t)BB * KK;

  // ws: f32 region | bf16 region (f32 region = 6,533,024 floats, 16B-aligned end)
  float* agg    = (float*)d_ws;                    // N*128 (aliased by g1f later)
  float* gate   = agg   + (size_t)NN * IN_C;       // N
  float* aexp   = gate  + NN;                      // N
  float* gmax   = aexp  + NN;                      // B
  float* denom  = gmax  + BB;                      // B
  float* pooled = denom + BB;                      // B*256
  float* fend   = pooled + (size_t)BB * HID_C;
  unsigned short* h0b  = (unsigned short*)fend;    // N*128 bf16
  unsigned short* h1b  = h0b + (size_t)NN * IN_C;  // N*256
  unsigned short* h2b  = h1b + (size_t)NN * HID_C; // N*256
  unsigned short* Wet  = h2b + (size_t)NN * HID_C; // 128*64
  unsigned short* W1t  = Wet + 128 * 64;           // 256*128
  unsigned short* W2t  = W1t + 256 * 128;          // 256*256
  unsigned short* Wg1t = W2t + 256 * 256;          // 128*256
  float* g1f = agg;                                // alias: agg dead after k_h0

  k_prep<<<256, 256, 0, stream>>>(We, W1, W2, Wg1, Wet, W1t, W2t, Wg1t);
  k_init<<<(NN * IN_C + 255) / 256, 256, 0, stream>>>(agg, gmax, denom, pooled);
  k_edge<<<EE / 128, 256, 0, stream>>>(x, ei, ea, Wet, be, agg);
  k_h0<<<(NN * IN_C + 255) / 256, 256, 0, stream>>>(agg, x, h0b);
  // h1 = relu(h0 @ W1 + b1) -> bf16
  k_gemm<128, true,  false, true ><<<dim3(782, 2), 256, 0, stream>>>(h0b, W1t, b1, (float*)0, h1b, NN, HID_C);
  // h2 = h1 @ W2 + b2 -> bf16
  k_gemm<256, false, false, true ><<<dim3(782, 2), 256, 0, stream>>>(h1b, W2t, b2, (float*)0, h2b, NN, HID_C);
  // g1 = relu(h2 @ Wg1 + bg1) -> f32 (into agg alias)
  k_gemm<256, true,  true,  false><<<dim3(782, 1), 256, 0, stream>>>(h2b, Wg1t, bg1, g1f, (unsigned short*)0, NN, G1_C);
  k_gate2<<<2048, 64, 0, stream>>>(g1f, Wg2, bg2, gate, NN);
  k_gmax  <<<(NN + 255) / 256, 256, 0, stream>>>(gate, batch, gmax, NN);
  k_expsum<<<(NN + 255) / 256, 256, 0, stream>>>(gate, batch, gmax, aexp, denom, NN);
  k_pool  <<<(NN + 255) / 256, 256, 0, stream>>>(h2b, aexp, denom, batch, pooled, NN);
  k_head<<<BB, 256, 0, stream>>>(pooled, Wh, bh, out_logits, out_pooled);
}

// Round 5
// 895.470 us; speedup vs baseline: 1.8861x; 1.0410x over previous
//
#include <hip/hip_runtime.h>
#include <stdint.h>

// Problem constants
#define NN    50000
#define EE    800000
#define IN_C  128
#define ED_C  64
#define HID_C 256
#define BB    128
#define KK    1000
#define G1_C  128
#define NV    50176   // NN padded to 196*256 for scan

// Dtype model (R1/R2 forensics): fp32 inputs, int32 indices, fp32 outputs.
// R4 counters: k_edge atomic-bound (252G dword-atomics/s); k_gemm frag loads
// were 16-line gathers. R5: sort-by-dst + run-merged atomics; LDS-staged gemm.

typedef __attribute__((ext_vector_type(8))) short bfrag;   // 8 x bf16
typedef __attribute__((ext_vector_type(4))) float f4acc;   // 4 x f32 acc

__device__ __forceinline__ unsigned short f2bs(float f){   // f32 -> bf16 (RNE)
  unsigned u = __float_as_uint(f);
  return (unsigned short)((u + 0x7fffu + ((u >> 16) & 1u)) >> 16);
}
__device__ __forceinline__ float bs2f(unsigned short s){
  return __uint_as_float(((unsigned)s) << 16);
}

__device__ __forceinline__ void atomicMaxFloat(float* addr, float val){
  int old = __float_as_int(*addr);
  while (__int_as_float(old) < val){
    int assumed = old;
    old = atomicCAS((int*)addr, assumed, __float_as_int(val));
    if (old == assumed) break;
  }
}

// ---------------- prep: cast+transpose weights to bf16 (Wt[n][k] = W[k][n]) --
__global__ __launch_bounds__(256) void k_prep(
    const float* __restrict__ We, const float* __restrict__ W1,
    const float* __restrict__ W2, const float* __restrict__ Wg1,
    unsigned short* __restrict__ Wet, unsigned short* __restrict__ W1t,
    unsigned short* __restrict__ W2t, unsigned short* __restrict__ Wg1t)
{
  int i = blockIdx.x * 256 + threadIdx.x;
  if (i < 128 * 64){ int c = i >> 6, k = i & 63;  Wet[i]  = f2bs(We[k * 128 + c]); }
  if (i < 256 * 128){ int n = i >> 7, k = i & 127; W1t[i]  = f2bs(W1[k * 256 + n]); }
  if (i < 256 * 256){ int n = i >> 8, k = i & 255; W2t[i]  = f2bs(W2[k * 256 + n]); }
  if (i < 128 * 256){ int n = i >> 8, k = i & 255; Wg1t[i] = f2bs(Wg1[k * 128 + n]); }
}

// ---------------- init: zero agg/cnt/fill/aux/denom/pooled, gmax=-1e30 ----
__global__ __launch_bounds__(256) void k_init(float* __restrict__ agg,
                                              int* __restrict__ cnt,
                                              int* __restrict__ fill,
                                              int* __restrict__ aux,
                                              float* __restrict__ gmax,
                                              float* __restrict__ denom,
                                              float* __restrict__ pooled){
  size_t i = (size_t)blockIdx.x * 256 + threadIdx.x;
  if (i < (size_t)NN * IN_C) agg[i] = 0.f;
  if (i < NV){ cnt[i] = 0; fill[i] = 0; }
  if (i < 256) aux[i] = 0;
  if (i < BB){ gmax[i] = -1e30f; denom[i] = 0.f; }
  if (i < BB * HID_C) pooled[i] = 0.f;
}

// ---------------- counting sort by dst: hist -> scan -> scatter ----------
__global__ __launch_bounds__(256) void k_hist(const int* __restrict__ ei,
                                              int* __restrict__ cnt){
  int e = blockIdx.x * 256 + threadIdx.x;
  if (e < EE) atomicAdd(&cnt[ei[EE + e]], 1);
}

__global__ __launch_bounds__(256) void k_scan1(const int* __restrict__ cnt,
                                               int* __restrict__ off,
                                               int* __restrict__ aux){
  __shared__ int s[256];
  int t = threadIdx.x, i = blockIdx.x * 256 + t;
  int val = cnt[i];
  s[t] = val; __syncthreads();
#pragma unroll
  for (int o = 1; o < 256; o <<= 1){
    int v = (t >= o) ? s[t - o] : 0;
    __syncthreads();
    s[t] += v;
    __syncthreads();
  }
  off[i] = s[t] - val;
  if (t == 255) aux[blockIdx.x] = s[255];
}

__global__ __launch_bounds__(256) void k_scan2(int* __restrict__ aux){
  __shared__ int s[256];
  int t = threadIdx.x;
  int val = aux[t];
  s[t] = val; __syncthreads();
#pragma unroll
  for (int o = 1; o < 256; o <<= 1){
    int v = (t >= o) ? s[t - o] : 0;
    __syncthreads();
    s[t] += v;
    __syncthreads();
  }
  aux[t] = s[t] - val;
}

__global__ __launch_bounds__(256) void k_scan3(int* __restrict__ off,
                                               const int* __restrict__ aux){
  int i = blockIdx.x * 256 + threadIdx.x;
  off[i] += aux[blockIdx.x];
}

__global__ __launch_bounds__(256) void k_scatter(const int* __restrict__ ei,
                                                 const int* __restrict__ off,
                                                 int* __restrict__ fill,
                                                 uint4* __restrict__ sorted){
  int e = blockIdx.x * 256 + threadIdx.x;
  if (e < EE){
    int s = ei[e], d = ei[EE + e];
    int pos = off[d] + atomicAdd(&fill[d], 1);
    sorted[pos] = make_uint4((unsigned)e, (unsigned)s, (unsigned)d, 0u);
  }
}

// ---------------- edge stage (MFMA, dst-sorted, run-merged atomics) ------
// Block = 256 thr / 4 waves; tile = 128 sorted slots x 128 channels.
__global__ __launch_bounds__(256) void k_edge2(
    const float* __restrict__ x, const uint4* __restrict__ sorted,
    const float* __restrict__ edge_attr,
    const unsigned short* __restrict__ Wet, const float* __restrict__ be,
    float* __restrict__ agg)
{
  __shared__ unsigned short eaS[128 * 72];
  __shared__ uint4 sE[128];
  const int tid = threadIdx.x;
  const int e0 = blockIdx.x * 128;
  if (tid < 128) sE[tid] = sorted[e0 + tid];
  __syncthreads();
#pragma unroll
  for (int t = 0; t < 8; ++t){
    int f4 = t * 256 + tid;
    int er = f4 >> 4;
    int kk = (f4 & 15) * 4;
    int eid = (int)sE[er].x;
    const float4 v = *(const float4*)(edge_attr + (size_t)eid * ED_C + kk);
    unsigned p0 = (unsigned)f2bs(v.x) | ((unsigned)f2bs(v.y) << 16);
    unsigned p1 = (unsigned)f2bs(v.z) | ((unsigned)f2bs(v.w) << 16);
    *(uint2*)&eaS[er * 72 + kk] = make_uint2(p0, p1);
  }
  __syncthreads();

  const int lane = tid & 63, wv = tid >> 6;
  const int q = lane >> 4, l15 = lane & 15;

  f4acc acc[2][8];
  const f4acc zz = {0.f, 0.f, 0.f, 0.f};
#pragma unroll
  for (int mt = 0; mt < 2; ++mt)
#pragma unroll
    for (int nt = 0; nt < 8; ++nt) acc[mt][nt] = zz;

#pragma unroll
  for (int ks = 0; ks < 2; ++ks){
    bfrag a[2], b[8];
#pragma unroll
    for (int mt = 0; mt < 2; ++mt){
      int m = wv * 32 + mt * 16 + l15;
      a[mt] = *(const bfrag*)&eaS[m * 72 + ks * 32 + q * 8];
    }
#pragma unroll
    for (int nt = 0; nt < 8; ++nt){
      int c = nt * 16 + l15;
      b[nt] = *(const bfrag*)(Wet + c * ED_C + ks * 32 + q * 8);
    }
#pragma unroll
    for (int mt = 0; mt < 2; ++mt)
#pragma unroll
      for (int nt = 0; nt < 8; ++nt)
        acc[mt][nt] = __builtin_amdgcn_mfma_f32_16x16x32_bf16(a[mt], b[nt], acc[mt][nt], 0, 0, 0);
  }

  float bev[8];
#pragma unroll
  for (int nt = 0; nt < 8; ++nt) bev[nt] = be[nt * 16 + l15];

#pragma unroll
  for (int mt = 0; mt < 2; ++mt){
    const int g = wv * 32 + mt * 16 + q * 4;        // quad-group base row (4 consecutive sorted slots)
    int sr[4], dr[4];
#pragma unroll
    for (int r = 0; r < 4; ++r){ sr[r] = (int)sE[g + r].y; dr[r] = (int)sE[g + r].z; }
#pragma unroll
    for (int nt = 0; nt < 8; ++nt){
      int c = nt * 16 + l15;
      float run = 0.f; int dprev = dr[0];
#pragma unroll
      for (int r = 0; r < 4; ++r){
        float v = acc[mt][nt][r] + bev[nt] + x[(size_t)sr[r] * IN_C + c];
        v = v > 0.f ? v : 0.f;
        if (dr[r] != dprev){
          atomicAdd(&agg[(size_t)dprev * IN_C + c], run);
          run = 0.f; dprev = dr[r];
        }
        run += v;
      }
      atomicAdd(&agg[(size_t)dprev * IN_C + c], run);
    }
  }
}

// ---------------- h0 = agg + x -> bf16 ----------------
__global__ __launch_bounds__(256) void k_h0(const float* __restrict__ agg,
                                            const float* __restrict__ x,
                                            unsigned short* __restrict__ h0b){
  int i = blockIdx.x * 256 + threadIdx.x;
  if (i < NN * IN_C) h0b[i] = f2bs(agg[i] + x[i]);
}

// ---------------- MFMA GEMM with LDS-staged fragments --------------------
// out[m][c] = A[m][:K].Wt[c][:K] + bias[c]; block 64m x 128n, 4 waves 2x2.
// A/B sub-tiles staged per 32-k step; 40-short row stride (80B: 16B-aligned,
// <=2-way LDS bank aliasing = free).
template<int K, bool RELU, bool OF32, bool OB16>
__global__ __launch_bounds__(256) void k_gemm(
    const unsigned short* __restrict__ A, const unsigned short* __restrict__ Wt,
    const float* __restrict__ bias, float* __restrict__ outf,
    unsigned short* __restrict__ outb, int M, int Ntot)
{
  __shared__ unsigned short aS[64 * 40];
  __shared__ unsigned short bS[128 * 40];
  const int tid = threadIdx.x;
  const int lane = tid & 63, wv = tid >> 6;
  const int wi = wv >> 1, wj = wv & 1;
  const int q = lane >> 4, l15 = lane & 15;
  const int mb0 = blockIdx.x * 64;
  const int nb0 = blockIdx.y * 128;
  const int arow = tid >> 2, achk = tid & 3;

  f4acc acc[2][4];
  const f4acc zz = {0.f, 0.f, 0.f, 0.f};
#pragma unroll
  for (int mt = 0; mt < 2; ++mt)
#pragma unroll
    for (int nt = 0; nt < 4; ++nt) acc[mt][nt] = zz;

  for (int ks = 0; ks < K / 32; ++ks){
    {
      int m = mb0 + arow; if (m >= M) m = M - 1;
      const uint4 v = *(const uint4*)(A + (size_t)m * K + ks * 32 + achk * 8);
      *(uint4*)&aS[arow * 40 + achk * 8] = v;
    }
#pragma unroll
    for (int i = 0; i < 2; ++i){
      int idx = i * 256 + tid;
      int row = idx >> 2, chk = idx & 3;
      const uint4 v = *(const uint4*)(Wt + (size_t)(nb0 + row) * K + ks * 32 + chk * 8);
      *(uint4*)&bS[row * 40 + chk * 8] = v;
    }
    __syncthreads();
    bfrag a[2], b[4];
#pragma unroll
    for (int mt = 0; mt < 2; ++mt)
      a[mt] = *(const bfrag*)&aS[(wi * 32 + mt * 16 + l15) * 40 + q * 8];
#pragma unroll
    for (int nt = 0; nt < 4; ++nt)
      b[nt] = *(const bfrag*)&bS[(wj * 64 + nt * 16 + l15) * 40 + q * 8];
#pragma unroll
    for (int mt = 0; mt < 2; ++mt)
#pragma unroll
      for (int nt = 0; nt < 4; ++nt)
        acc[mt][nt] = __builtin_amdgcn_mfma_f32_16x16x32_bf16(a[mt], b[nt], acc[mt][nt], 0, 0, 0);
    __syncthreads();
  }

  const int mb = mb0 + wi * 32;
  const int nb = nb0 + wj * 64;
#pragma unroll
  for (int nt = 0; nt < 4; ++nt){
    int c = nb + nt * 16 + l15;
    float bv = bias[c];
#pragma unroll
    for (int mt = 0; mt < 2; ++mt){
#pragma unroll
      for (int r = 0; r < 4; ++r){
        int m = mb + mt * 16 + q * 4 + r;
        if (m < M){
          float v = acc[mt][nt][r] + bv;
          if (RELU) v = v > 0.f ? v : 0.f;
          if (OF32) outf[(size_t)m * Ntot + c] = v;
          if (OB16) outb[(size_t)m * Ntot + c] = f2bs(v);
        }
      }
    }
  }
}

// ---------------- gate2: gate[r] = g1[r,:128].Wg2 + bg2 (wave/row) -------
__global__ __launch_bounds__(256) void k_gate2(const float* __restrict__ g1,
                                               const float* __restrict__ Wg2,
                                               const float* __restrict__ bg2,
                                               float* __restrict__ gate, int nrows){
  const int lane = threadIdx.x & 63, wv = threadIdx.x >> 6;
  const float2 w2 = *(const float2*)(Wg2 + lane * 2);
  const float bg = bg2[0];
  for (int r = blockIdx.x * 4 + wv; r < nrows; r += gridDim.x * 4){
    const float2 a2 = *(const float2*)(g1 + (size_t)r * G1_C + lane * 2);
    float p = a2.x * w2.x + a2.y * w2.y;
#pragma unroll
    for (int off = 32; off > 0; off >>= 1) p += __shfl_down(p, off);
    if (lane == 0) gate[r] = p + bg;
  }
}

// ---------------- segment max (batch sorted; block pre-reduce) ----------
__global__ __launch_bounds__(256) void k_gmax(const float* __restrict__ gate,
                                              const int* __restrict__ batch,
                                              float* __restrict__ gmax, int nrows){
  __shared__ float red[256];
  const int tid = threadIdx.x;
  const int n0 = blockIdx.x * 256;
  const int n = n0 + tid;
  const int nlast = (n0 + 255 < nrows) ? n0 + 255 : nrows - 1;
  const int bmin = batch[n0], bmax = batch[nlast];
  float val = -3e38f; int b = bmax;
  if (n < nrows){ b = batch[n]; val = gate[n]; }
  for (int bb = bmin; bb <= bmax; ++bb){
    red[tid] = (b == bb) ? val : -3e38f;
    __syncthreads();
    for (int s = 128; s > 0; s >>= 1){
      if (tid < s) red[tid] = fmaxf(red[tid], red[tid + s]);
      __syncthreads();
    }
    if (tid == 0 && red[0] > -1e37f) atomicMaxFloat(&gmax[bb], red[0]);
    __syncthreads();
  }
}

// ---------------- a = exp(gate - gmax[b]); denom[b] += a ----------------
__global__ __launch_bounds__(256) void k_expsum(const float* __restrict__ gate,
                                                const int* __restrict__ batch,
                                                const float* __restrict__ gmax,
                                                float* __restrict__ aexp,
                                                float* __restrict__ denom, int nrows){
  __shared__ float red[256];
  const int tid = threadIdx.x;
  const int n0 = blockIdx.x * 256;
  const int n = n0 + tid;
  const int nlast = (n0 + 255 < nrows) ? n0 + 255 : nrows - 1;
  const int bmin = batch[n0], bmax = batch[nlast];
  float val = 0.f; int b = bmax;
  if (n < nrows){
    b = batch[n];
    val = expf(gate[n] - gmax[b]);
    aexp[n] = val;
  }
  for (int bb = bmin; bb <= bmax; ++bb){
    red[tid] = (b == bb) ? val : 0.f;
    __syncthreads();
    for (int s = 128; s > 0; s >>= 1){
      if (tid < s) red[tid] += red[tid + s];
      __syncthreads();
    }
    if (tid == 0 && red[0] != 0.f) atomicAdd(&denom[bb], red[0]);
    __syncthreads();
  }
}

// ---------------- pooled[b] += (a/denom[b]) * h2[n] ----------------
__global__ __launch_bounds__(256) void k_pool(const unsigned short* __restrict__ h2b,
                                              const float* __restrict__ aexp,
                                              const float* __restrict__ denom,
                                              const int* __restrict__ batch,
                                              float* __restrict__ pooled, int nrows){
  const int c = threadIdx.x;
  const int n0 = blockIdx.x * 256;
  int n1 = n0 + 256; if (n1 > nrows) n1 = nrows;
  float acc = 0.f;
  int curb = batch[n0];
  for (int n = n0; n < n1; ++n){
    int b = batch[n];
    if (b != curb){
      atomicAdd(&pooled[(size_t)curb * HID_C + c], acc);
      acc = 0.f; curb = b;
    }
    float wgt = aexp[n] / denom[b];
    acc = fmaf(wgt, bs2f(h2b[(size_t)n * HID_C + c]), acc);
  }
  atomicAdd(&pooled[(size_t)curb * HID_C + c], acc);
}

// ---------------- head: logits = pooled @ Wh + bh ----------------
__global__ __launch_bounds__(256) void k_head(const float* __restrict__ pooled,
                                              const float* __restrict__ Wh,
                                              const float* __restrict__ bh,
                                              float* __restrict__ out_logits,
                                              float* __restrict__ out_pooled){
  __shared__ float p[HID_C];
  const int b = blockIdx.x, t = threadIdx.x;
  float pv = pooled[(size_t)b * HID_C + t];
  p[t] = pv;
  out_pooled[(size_t)b * HID_C + t] = pv;
  __syncthreads();
  for (int c = t; c < KK; c += 256){
    float acc = bh[c];
#pragma unroll 8
    for (int k = 0; k < HID_C; ++k)
      acc = fmaf(p[k], Wh[k * KK + c], acc);
    out_logits[(size_t)b * KK + c] = acc;
  }
}

extern "C" void kernel_launch(void* const* d_in, const int* in_sizes, int n_in,
                              void* d_out, int out_size, void* d_ws, size_t ws_size,
                              hipStream_t stream) {
  const float* x   = (const float*)d_in[0];
  const int*   ei  = (const int*)d_in[1];
  const float* ea  = (const float*)d_in[2];
  const int*   batch = (const int*)d_in[3];
  const float* We  = (const float*)d_in[4];
  const float* be  = (const float*)d_in[5];
  const float* W1  = (const float*)d_in[6];
  const float* b1  = (const float*)d_in[7];
  const float* W2  = (const float*)d_in[8];
  const float* b2  = (const float*)d_in[9];
  const float* Wg1 = (const float*)d_in[10];
  const float* bg1 = (const float*)d_in[11];
  const float* Wg2 = (const float*)d_in[12];
  const float* bg2 = (const float*)d_in[13];
  const float* Wh  = (const float*)d_in[14];
  const float* bh  = (const float*)d_in[15];

  float* out_logits = (float*)d_out;
  float* out_pooled = out_logits + (size_t)BB * KK;

  // ws layout: f32 region | h0b | h1b (aliased by sort scratch) | h2b | weights
  float* agg    = (float*)d_ws;                    // N*128 (g1f alias later)
  float* gate   = agg   + (size_t)NN * IN_C;       // N
  float* aexp   = gate  + NN;                      // N
  float* gmax   = aexp  + NN;                      // B
  float* denom  = gmax  + BB;                      // B
  float* pooled = denom + BB;                      // B*256
  float* fend   = pooled + (size_t)BB * HID_C;     // 16B-aligned
  unsigned short* h0b  = (unsigned short*)fend;    // N*128 bf16
  unsigned short* h1b  = h0b + (size_t)NN * IN_C;  // N*256 bf16 (25.6MB)
  unsigned short* h2b  = h1b + (size_t)NN * HID_C; // N*256 bf16
  unsigned short* Wet  = h2b + (size_t)NN * HID_C; // 128*64
  unsigned short* W1t  = Wet + 128 * 64;
  unsigned short* W2t  = W1t + 256 * 128;
  unsigned short* Wg1t = W2t + 256 * 256;
  float* g1f = agg;                                // alias: agg dead after k_h0
  // sort scratch aliases h1b region (dead until gemm1): 12.8MB + 0.6MB < 25.6MB
  uint4* sorted = (uint4*)h1b;                     // EE * 16B
  int* cnt  = (int*)(sorted + EE);                 // NV
  int* off  = cnt + NV;                            // NV
  int* fill = off + NV;                            // NV
  int* aux  = fill + NV;                           // 256

  k_prep<<<256, 256, 0, stream>>>(We, W1, W2, Wg1, Wet, W1t, W2t, Wg1t);
  k_init<<<(NN * IN_C + 255) / 256, 256, 0, stream>>>(agg, cnt, fill, aux, gmax, denom, pooled);
  // counting sort by dst
  k_hist   <<<(EE + 255) / 256, 256, 0, stream>>>(ei, cnt);
  k_scan1  <<<NV / 256, 256, 0, stream>>>(cnt, off, aux);
  k_scan2  <<<1, 256, 0, stream>>>(aux);
  k_scan3  <<<NV / 256, 256, 0, stream>>>(off, aux);
  k_scatter<<<(EE + 255) / 256, 256, 0, stream>>>(ei, off, fill, sorted);
  // edge projection + message + run-merged scatter-add
  k_edge2<<<EE / 128, 256, 0, stream>>>(x, sorted, ea, Wet, be, agg);
  k_h0<<<(NN * IN_C + 255) / 256, 256, 0, stream>>>(agg, x, h0b);
  // MLP + gate GEMMs (sort scratch dead from here; h1b reused)
  k_gemm<128, true,  false, true ><<<dim3(782, 2), 256, 0, stream>>>(h0b, W1t, b1, (float*)0, h1b, NN, HID_C);
  k_gemm<256, false, false, true ><<<dim3(782, 2), 256, 0, stream>>>(h1b, W2t, b2, (float*)0, h2b, NN, HID_C);
  k_gemm<256, true,  true,  false><<<dim3(782, 1), 256, 0, stream>>>(h2b, Wg1t, bg1, g1f, (unsigned short*)0, NN, G1_C);
  k_gate2<<<3125, 256, 0, stream>>>(g1f, Wg2, bg2, gate, NN);
  k_gmax  <<<(NN + 255) / 256, 256, 0, stream>>>(gate, batch, gmax, NN);
  k_expsum<<<(NN + 255) / 256, 256, 0, stream>>>(gate, batch, gmax, aexp, denom, NN);
  k_pool  <<<(NN + 255) / 256, 256, 0, stream>>>(h2b, aexp, denom, batch, pooled, NN);
  k_head<<<BB, 256, 0, stream>>>(pooled, Wh, bh, out_logits, out_pooled);
}